// Round 13
// baseline (119.709 us; speedup 1.0000x reference)
//
#include <hip/hip_runtime.h>
#include <hip/hip_bf16.h>

// Problem constants
constexpr int BATCH = 4096;
constexpr int IN    = 512;
constexpr int OUT   = 512;
constexpr int ORD   = 8;
constexpr int NK    = ORD + 1;        // 9
constexpr float FA  = 1.0f, FB = 1.0f;

// GEMM inner dim EXCLUDES k=0 (J0 == 1 -> bias term), KP = 4096
constexpr int KP     = IN * ORD;
constexpr int SPLITK = 8;                      // 1024 blocks -> 3 blocks/CU resident
constexpr int KT     = KP / (32 * SPLITK);     // 16 K-steps (of 32) per block
constexpr int KS_TOT = KP / 32;                // 128 k-steps total

// Fragment-major layouts (written by prep, read by gemm):
//   A2[mt][ks] = 64 lanes x 16B, element (b = mt*16 + (lane&15),
//                K = ks*32 + (lane>>4)*8 + j)  -- exactly the MFMA A-operand.
//   B2[nt][ks] likewise with o rows. One wave frag load = lane*16B, coalesced.

typedef __attribute__((ext_vector_type(8))) short short8;   // 8 bf16
typedef __attribute__((ext_vector_type(4))) float floatx4;  // MFMA C/D

__device__ __forceinline__ float bf16bits_to_f32(short s) {
    union { unsigned int u; float f; } cv;
    cv.u = ((unsigned int)(unsigned short)s) << 16;
    return cv.f;
}
__device__ __forceinline__ short f32_to_bf16bits(float f) {
    __hip_bfloat16 h = __float2bfloat16(f);
    return *(short*)&h;
}

// ---------------------------------------------------------------------------
// Kernel 1 (fused prep):
//  blocks [0,1024):      Jacobi -> A2 fragment-major
//  blocks [1024,1152):   coeff*w -> B2 fragment-major
//  blocks [1152,1280):   bias[o] = sum_i coeff[o,i,0]*w[o,i] (1 wave per o)
// ---------------------------------------------------------------------------
__global__ __launch_bounds__(256) void prep(const float* __restrict__ x,
                                            const float* __restrict__ w,
                                            const float* __restrict__ coeff,
                                            short* __restrict__ A2,
                                            short* __restrict__ B2,
                                            float* __restrict__ bias) {
    const int bid  = blockIdx.x;
    const int tid  = threadIdx.x;
    const int lane = tid & 63;
    const int quad = lane >> 4;
    const int l15  = lane & 15;

    if (bid < 1024) {
        // ---- Jacobi branch: mt = bid/4, thread: b = mt*16+l15, 8 i's ----
        const int mt  = bid >> 2;
        const int sub = ((bid & 3) << 2) + (tid >> 6);   // 0..15
        const int b   = mt * 16 + l15;
        const int i0  = sub * 32 + quad * 8;
        const float* xr = x + (size_t)b * IN + i0;
        float t[8];
#pragma unroll
        for (int e = 0; e < 8; ++e) {
            float xc = fminf(fmaxf(xr[e], -9.0f), 9.0f);
            float ex = __expf(2.0f * xc);
            t[e] = (ex - 1.0f) / (ex + 1.0f);
        }
        float pp[8], pc[8];
#pragma unroll
        for (int e = 0; e < 8; ++e) {
            pp[e] = 1.0f;
            pc[e] = 0.5f * (FA + FB + 2.0f) * t[e] - 0.5f * (FA - FB);
        }
        {
            short8 v;
#pragma unroll
            for (int e = 0; e < 8; ++e) v[e] = f32_to_bf16bits(pc[e]);
            *(short8*)(A2 + (((size_t)mt * KS_TOT + sub) * 64 + lane) * 8) = v;
        }
#pragma unroll
        for (int n = 2; n <= ORD; ++n) {
            float fn = (float)n;
            float k1 = (2.f*fn+FA+FB)*(2.f*fn+FA+FB-1.f) / (2.f*fn*(fn+FA+FB));
            float k2 = (2.f*fn+FA+FB-1.f)*(FA*FA-FB*FB) /
                       (2.f*fn*(fn+FA+FB)*(2.f*fn+FA+FB-2.f));
            float k3 = (fn+FA-1.f)*(fn+FB-1.f)*(2.f*fn+FA+FB) /
                       (fn*(fn+FA+FB)*(2.f*fn+FA+FB-2.f));
            short8 v;
#pragma unroll
            for (int e = 0; e < 8; ++e) {
                float nx = (k1*t[e] + k2)*pc[e] - k3*pp[e];
                pp[e] = pc[e]; pc[e] = nx;
                v[e] = f32_to_bf16bits(nx);
            }
            const int ks = (n - 1) * 16 + sub;
            *(short8*)(A2 + (((size_t)mt * KS_TOT + ks) * 64 + lane) * 8) = v;
        }
    } else if (bid < 1152) {
        // ---- coeff*w branch: nt = (bid-1024)/4, o = nt*16+l15, 8 i's ----
        const int b2  = bid - 1024;
        const int nt  = b2 >> 2;
        const int sub = ((b2 & 3) << 2) + (tid >> 6);
        const int o   = nt * 16 + l15;
        const int i0  = sub * 32 + quad * 8;
        const float* wr = w + (size_t)o * IN + i0;
        float wv[8];
#pragma unroll
        for (int e = 0; e < 8; ++e) wv[e] = wr[e];
        const float* cf = coeff + ((size_t)o * IN + i0) * NK;  // [e][k] stride 9
#pragma unroll
        for (int n = 1; n <= ORD; ++n) {
            short8 v;
#pragma unroll
            for (int e = 0; e < 8; ++e)
                v[e] = f32_to_bf16bits(cf[(size_t)e * NK + n] * wv[e]);
            const int ks = (n - 1) * 16 + sub;
            *(short8*)(B2 + (((size_t)nt * KS_TOT + ks) * 64 + lane) * 8) = v;
        }
    } else {
        // ---- bias branch: 128 blocks, one wave per output o ----
        const int bb = bid - 1152;                       // 0..127
        const int o  = bb * 4 + (tid >> 6);
        const float* cf = coeff + (size_t)o * IN * NK;
        const float* wr = w + (size_t)o * IN;
        float acc = 0.0f;
#pragma unroll
        for (int r = 0; r < IN / 64; ++r) {
            int i = r * 64 + lane;
            acc = fmaf(cf[(size_t)i * NK], wr[i], acc);
        }
#pragma unroll
        for (int off = 32; off >= 1; off >>= 1)
            acc += __shfl_xor(acc, off, 64);
        if (lane == 0) bias[o] = acc;
    }
}

// ---------------------------------------------------------------------------
// Kernel 2: split-K GEMM, no LDS/barriers, 2-SLOT REGISTER PIPELINE (r11 win,
// r12's 4-slot regressed: live-range blowup). Changes vs r11:
//  - loop peeled: refills unconditional in main loop, branch-free tail
//  - SPLITK=8 (1024 blocks) + __launch_bounds__(256,3): 3 blocks/CU resident
//    -> 3 waves/SIMD covering the cold-HBM A2 latency (the binding stall).
// ---------------------------------------------------------------------------
__global__ __launch_bounds__(256, 3) void gemm_splitk(
        const short* __restrict__ A2,   // [256][128] x 1KB lines
        const short* __restrict__ B2,   // [32][128]  x 1KB lines
        __hip_bfloat16* __restrict__ P) // [SPLITK][4096][512] bf16
{
    const int tid  = threadIdx.x;
    const int lane = tid & 63;
    const int quad = lane >> 4;
    const int l15  = lane & 15;
    const int mw   = (tid >> 6) & 1;
    const int nw   = tid >> 7;
    const int bx = blockIdx.x;          // 0..31  (m-tiles of 128)
    const int by = blockIdx.y;          // 0..3   (n-tiles of 128)
    const int z  = blockIdx.z;          // 0..7

    const short* pa[4];
    const short* pb[4];
#pragma unroll
    for (int i = 0; i < 4; ++i)
        pa[i] = A2 + (((size_t)(bx * 8 + mw * 4 + i) * KS_TOT + z * KT) * 64 + lane) * 8;
#pragma unroll
    for (int j = 0; j < 4; ++j)
        pb[j] = B2 + (((size_t)(by * 8 + nw * 4 + j) * KS_TOT + z * KT) * 64 + lane) * 8;

    floatx4 acc[4][4];
#pragma unroll
    for (int i = 0; i < 4; ++i)
#pragma unroll
        for (int j = 0; j < 4; ++j) acc[i][j] = (floatx4)0.0f;

    // 2-slot pipeline registers: slot0 holds even k, slot1 odd k
    short8 a0[4], b0[4], a1[4], b1[4];
#pragma unroll
    for (int i = 0; i < 4; ++i) { a0[i] = *(const short8*)(pa[i]);       b0[i] = *(const short8*)(pb[i]); }
#pragma unroll
    for (int i = 0; i < 4; ++i) { a1[i] = *(const short8*)(pa[i] + 512); b1[i] = *(const short8*)(pb[i] + 512); }

    // main loop: kt = 0 .. KT-4, refills unconditional (kt+3 <= KT-1)
    for (int kt = 0; kt < KT - 2; kt += 2) {
#pragma unroll
        for (int i = 0; i < 4; ++i)
#pragma unroll
            for (int j = 0; j < 4; ++j)
                acc[i][j] = __builtin_amdgcn_mfma_f32_16x16x32_bf16(
                                a0[i], b0[j], acc[i][j], 0, 0, 0);
#pragma unroll
        for (int i = 0; i < 4; ++i) {
            a0[i] = *(const short8*)(pa[i] + (kt + 2) * 512);
            b0[i] = *(const short8*)(pb[i] + (kt + 2) * 512);
        }
#pragma unroll
        for (int i = 0; i < 4; ++i)
#pragma unroll
            for (int j = 0; j < 4; ++j)
                acc[i][j] = __builtin_amdgcn_mfma_f32_16x16x32_bf16(
                                a1[i], b1[j], acc[i][j], 0, 0, 0);
#pragma unroll
        for (int i = 0; i < 4; ++i) {
            a1[i] = *(const short8*)(pa[i] + (kt + 3) * 512);
            b1[i] = *(const short8*)(pb[i] + (kt + 3) * 512);
        }
    }
    // tail: last two K-steps, no refills
#pragma unroll
    for (int i = 0; i < 4; ++i)
#pragma unroll
        for (int j = 0; j < 4; ++j)
            acc[i][j] = __builtin_amdgcn_mfma_f32_16x16x32_bf16(
                            a0[i], b0[j], acc[i][j], 0, 0, 0);
#pragma unroll
    for (int i = 0; i < 4; ++i)
#pragma unroll
        for (int j = 0; j < 4; ++j)
            acc[i][j] = __builtin_amdgcn_mfma_f32_16x16x32_bf16(
                            a1[i], b1[j], acc[i][j], 0, 0, 0);

    // epilogue: C/D layout col = lane&15, row = quad*4 + reg; bf16 partials
    __hip_bfloat16* Pz = P + (size_t)z * BATCH * OUT;
    const int m0 = bx * 128, n0 = by * 128;
#pragma unroll
    for (int i = 0; i < 4; ++i) {
        const int r0 = m0 + mw * 64 + i * 16 + quad * 4;
#pragma unroll
        for (int j = 0; j < 4; ++j) {
            const int c = n0 + nw * 64 + j * 16 + l15;
#pragma unroll
            for (int r = 0; r < 4; ++r)
                Pz[(size_t)(r0 + r) * OUT + c] = __float2bfloat16(acc[i][j][r]);
        }
    }
}

// ---------------------------------------------------------------------------
// Kernel 3: out[b,o] = sum_z P[z][b,o] + bias[o]   (8 outputs per thread)
// ---------------------------------------------------------------------------
__global__ __launch_bounds__(256) void reducek(const short* __restrict__ P,
                                               const float* __restrict__ bias,
                                               float* __restrict__ out) {
    const int j = blockIdx.x * 256 + threadIdx.x;
    const size_t base = (size_t)j * 8;
    constexpr size_t PLANE = (size_t)BATCH * OUT;

    float s[8];
    {
        short8 v = *(const short8*)(P + base);
#pragma unroll
        for (int e = 0; e < 8; ++e) s[e] = bf16bits_to_f32(v[e]);
    }
#pragma unroll
    for (int z = 1; z < SPLITK; ++z) {
        short8 v = *(const short8*)(P + z * PLANE + base);
#pragma unroll
        for (int e = 0; e < 8; ++e) s[e] += bf16bits_to_f32(v[e]);
    }
    const int o0 = (int)(base & (OUT - 1));
    const floatx4 b0 = *(const floatx4*)(bias + o0);
    const floatx4 b1 = *(const floatx4*)(bias + o0 + 4);
    floatx4 r0 = {s[0] + b0[0], s[1] + b0[1], s[2] + b0[2], s[3] + b0[3]};
    floatx4 r1 = {s[4] + b1[0], s[5] + b1[1], s[6] + b1[2], s[7] + b1[3]};
    *(floatx4*)(out + base)     = r0;
    *(floatx4*)(out + base + 4) = r1;
}

// ---------------------------------------------------------------------------
extern "C" void kernel_launch(void* const* d_in, const int* in_sizes, int n_in,
                              void* d_out, int out_size, void* d_ws, size_t ws_size,
                              hipStream_t stream) {
    const float* x     = (const float*)d_in[0];   // [4096,512]
    const float* w     = (const float*)d_in[1];   // [512,512]
    const float* coeff = (const float*)d_in[2];   // [512,512,9]
    float* out = (float*)d_out;                   // [4096,512]

    // workspace layout (bytes)
    char* ws = (char*)d_ws;
    short* A2 = (short*)ws;                                            // 33,554,432 B
    char* p1c = ws + (size_t)BATCH * KP * 2;
    short* B2 = (short*)p1c;                                           //  4,194,304 B
    char* p2c = p1c + (size_t)OUT * KP * 2;
    __hip_bfloat16* P = (__hip_bfloat16*)p2c;                          // 33,554,432 B
    float* bias = (float*)(p2c + (size_t)SPLITK * BATCH * OUT * 2);    //      2,048 B

    prep<<<1280, 256, 0, stream>>>(x, w, coeff, A2, B2, bias);
    gemm_splitk<<<dim3(32, 4, SPLITK), 256, 0, stream>>>(A2, B2, P);
    reducek<<<BATCH * OUT / 8 / 256, 256, 0, stream>>>((const short*)P, bias, out);
}

// Round 14
// 103.397 us; speedup vs baseline: 1.1578x; 1.1578x over previous
//
#include <hip/hip_runtime.h>
#include <hip/hip_bf16.h>

// Problem constants
constexpr int BATCH = 4096;
constexpr int IN    = 512;
constexpr int OUT   = 512;
constexpr int ORD   = 8;
constexpr int NK    = ORD + 1;        // 9
constexpr float FA  = 1.0f, FB = 1.0f;

// GEMM inner dim EXCLUDES k=0 (J0 == 1 -> bias term), KP = 4096
constexpr int KP     = IN * ORD;
constexpr int SPLITK = 4;                      // 512 blocks -> 2 blocks/CU (r11 optimum)
constexpr int KT     = KP / (32 * SPLITK);     // 32 K-steps (of 32) per block
constexpr int KS_TOT = KP / 32;                // 128 k-steps total

// Fragment-major layouts (written by prep, read by gemm):
//   A2[mt][ks] = 64 lanes x 16B, element (b = mt*16 + (lane&15),
//                K = ks*32 + (lane>>4)*8 + j)  -- exactly the MFMA A-operand.
//   B2[nt][ks] likewise with o rows. One wave frag load = lane*16B, coalesced.

typedef __attribute__((ext_vector_type(8))) short short8;   // 8 bf16
typedef __attribute__((ext_vector_type(4))) float floatx4;  // MFMA C/D

__device__ __forceinline__ float bf16bits_to_f32(short s) {
    union { unsigned int u; float f; } cv;
    cv.u = ((unsigned int)(unsigned short)s) << 16;
    return cv.f;
}
__device__ __forceinline__ short f32_to_bf16bits(float f) {
    __hip_bfloat16 h = __float2bfloat16(f);
    return *(short*)&h;
}

// ---------------------------------------------------------------------------
// Kernel 1 (fused prep):
//  blocks [0,1024):      Jacobi -> A2 fragment-major
//  blocks [1024,1152):   coeff*w -> B2 fragment-major
//  blocks [1152,1280):   bias[o] = sum_i coeff[o,i,0]*w[o,i] (1 wave per o)
// ---------------------------------------------------------------------------
__global__ __launch_bounds__(256) void prep(const float* __restrict__ x,
                                            const float* __restrict__ w,
                                            const float* __restrict__ coeff,
                                            short* __restrict__ A2,
                                            short* __restrict__ B2,
                                            float* __restrict__ bias) {
    const int bid  = blockIdx.x;
    const int tid  = threadIdx.x;
    const int lane = tid & 63;
    const int quad = lane >> 4;
    const int l15  = lane & 15;

    if (bid < 1024) {
        // ---- Jacobi branch: mt = bid/4, thread: b = mt*16+l15, 8 i's ----
        const int mt  = bid >> 2;
        const int sub = ((bid & 3) << 2) + (tid >> 6);   // 0..15
        const int b   = mt * 16 + l15;
        const int i0  = sub * 32 + quad * 8;
        const float* xr = x + (size_t)b * IN + i0;
        float t[8];
#pragma unroll
        for (int e = 0; e < 8; ++e) {
            float xc = fminf(fmaxf(xr[e], -9.0f), 9.0f);
            float ex = __expf(2.0f * xc);
            t[e] = (ex - 1.0f) / (ex + 1.0f);
        }
        float pp[8], pc[8];
#pragma unroll
        for (int e = 0; e < 8; ++e) {
            pp[e] = 1.0f;
            pc[e] = 0.5f * (FA + FB + 2.0f) * t[e] - 0.5f * (FA - FB);
        }
        {
            short8 v;
#pragma unroll
            for (int e = 0; e < 8; ++e) v[e] = f32_to_bf16bits(pc[e]);
            *(short8*)(A2 + (((size_t)mt * KS_TOT + sub) * 64 + lane) * 8) = v;
        }
#pragma unroll
        for (int n = 2; n <= ORD; ++n) {
            float fn = (float)n;
            float k1 = (2.f*fn+FA+FB)*(2.f*fn+FA+FB-1.f) / (2.f*fn*(fn+FA+FB));
            float k2 = (2.f*fn+FA+FB-1.f)*(FA*FA-FB*FB) /
                       (2.f*fn*(fn+FA+FB)*(2.f*fn+FA+FB-2.f));
            float k3 = (fn+FA-1.f)*(fn+FB-1.f)*(2.f*fn+FA+FB) /
                       (fn*(fn+FA+FB)*(2.f*fn+FA+FB-2.f));
            short8 v;
#pragma unroll
            for (int e = 0; e < 8; ++e) {
                float nx = (k1*t[e] + k2)*pc[e] - k3*pp[e];
                pp[e] = pc[e]; pc[e] = nx;
                v[e] = f32_to_bf16bits(nx);
            }
            const int ks = (n - 1) * 16 + sub;
            *(short8*)(A2 + (((size_t)mt * KS_TOT + ks) * 64 + lane) * 8) = v;
        }
    } else if (bid < 1152) {
        // ---- coeff*w branch: nt = (bid-1024)/4, o = nt*16+l15, 8 i's ----
        const int b2  = bid - 1024;
        const int nt  = b2 >> 2;
        const int sub = ((b2 & 3) << 2) + (tid >> 6);
        const int o   = nt * 16 + l15;
        const int i0  = sub * 32 + quad * 8;
        const float* wr = w + (size_t)o * IN + i0;
        float wv[8];
#pragma unroll
        for (int e = 0; e < 8; ++e) wv[e] = wr[e];
        const float* cf = coeff + ((size_t)o * IN + i0) * NK;  // [e][k] stride 9
#pragma unroll
        for (int n = 1; n <= ORD; ++n) {
            short8 v;
#pragma unroll
            for (int e = 0; e < 8; ++e)
                v[e] = f32_to_bf16bits(cf[(size_t)e * NK + n] * wv[e]);
            const int ks = (n - 1) * 16 + sub;
            *(short8*)(B2 + (((size_t)nt * KS_TOT + ks) * 64 + lane) * 8) = v;
        }
    } else {
        // ---- bias branch: 128 blocks, one wave per output o ----
        const int bb = bid - 1152;                       // 0..127
        const int o  = bb * 4 + (tid >> 6);
        const float* cf = coeff + (size_t)o * IN * NK;
        const float* wr = w + (size_t)o * IN;
        float acc = 0.0f;
#pragma unroll
        for (int r = 0; r < IN / 64; ++r) {
            int i = r * 64 + lane;
            acc = fmaf(cf[(size_t)i * NK], wr[i], acc);
        }
#pragma unroll
        for (int off = 32; off >= 1; off >>= 1)
            acc += __shfl_xor(acc, off, 64);
        if (lane == 0) bias[o] = acc;
    }
}

// ---------------------------------------------------------------------------
// Kernel 2: split-K GEMM, no LDS/barriers, 2-SLOT REGISTER PIPELINE.
// Exact r11 configuration (the measured optimum: SPLITK=4, 2 waves/SIMD cap)
// with ONE delta: K-loop peeled so refills are branch-free (r11 had two
// runtime `if` checks per iteration in the hot loop).
// ---------------------------------------------------------------------------
__global__ __launch_bounds__(256, 2) void gemm_splitk(
        const short* __restrict__ A2,   // [256][128] x 1KB lines
        const short* __restrict__ B2,   // [32][128]  x 1KB lines
        __hip_bfloat16* __restrict__ P) // [SPLITK][4096][512] bf16
{
    const int tid  = threadIdx.x;
    const int lane = tid & 63;
    const int quad = lane >> 4;
    const int l15  = lane & 15;
    const int mw   = (tid >> 6) & 1;
    const int nw   = tid >> 7;
    const int bx = blockIdx.x;          // 0..31  (m-tiles of 128)
    const int by = blockIdx.y;          // 0..3   (n-tiles of 128)
    const int z  = blockIdx.z;          // 0..3

    const short* pa[4];
    const short* pb[4];
#pragma unroll
    for (int i = 0; i < 4; ++i)
        pa[i] = A2 + (((size_t)(bx * 8 + mw * 4 + i) * KS_TOT + z * KT) * 64 + lane) * 8;
#pragma unroll
    for (int j = 0; j < 4; ++j)
        pb[j] = B2 + (((size_t)(by * 8 + nw * 4 + j) * KS_TOT + z * KT) * 64 + lane) * 8;

    floatx4 acc[4][4];
#pragma unroll
    for (int i = 0; i < 4; ++i)
#pragma unroll
        for (int j = 0; j < 4; ++j) acc[i][j] = (floatx4)0.0f;

    // 2-slot pipeline registers: slot0 holds even k, slot1 odd k
    short8 a0[4], b0[4], a1[4], b1[4];
#pragma unroll
    for (int i = 0; i < 4; ++i) { a0[i] = *(const short8*)(pa[i]);       b0[i] = *(const short8*)(pb[i]); }
#pragma unroll
    for (int i = 0; i < 4; ++i) { a1[i] = *(const short8*)(pa[i] + 512); b1[i] = *(const short8*)(pb[i] + 512); }

    // main loop: refills unconditional (kt+3 <= KT-1 for kt <= KT-4)
    for (int kt = 0; kt < KT - 2; kt += 2) {
#pragma unroll
        for (int i = 0; i < 4; ++i)
#pragma unroll
            for (int j = 0; j < 4; ++j)
                acc[i][j] = __builtin_amdgcn_mfma_f32_16x16x32_bf16(
                                a0[i], b0[j], acc[i][j], 0, 0, 0);
#pragma unroll
        for (int i = 0; i < 4; ++i) {
            a0[i] = *(const short8*)(pa[i] + (kt + 2) * 512);
            b0[i] = *(const short8*)(pb[i] + (kt + 2) * 512);
        }
#pragma unroll
        for (int i = 0; i < 4; ++i)
#pragma unroll
            for (int j = 0; j < 4; ++j)
                acc[i][j] = __builtin_amdgcn_mfma_f32_16x16x32_bf16(
                                a1[i], b1[j], acc[i][j], 0, 0, 0);
#pragma unroll
        for (int i = 0; i < 4; ++i) {
            a1[i] = *(const short8*)(pa[i] + (kt + 3) * 512);
            b1[i] = *(const short8*)(pb[i] + (kt + 3) * 512);
        }
    }
    // tail: last two K-steps, no refills
#pragma unroll
    for (int i = 0; i < 4; ++i)
#pragma unroll
        for (int j = 0; j < 4; ++j)
            acc[i][j] = __builtin_amdgcn_mfma_f32_16x16x32_bf16(
                            a0[i], b0[j], acc[i][j], 0, 0, 0);
#pragma unroll
    for (int i = 0; i < 4; ++i)
#pragma unroll
        for (int j = 0; j < 4; ++j)
            acc[i][j] = __builtin_amdgcn_mfma_f32_16x16x32_bf16(
                            a1[i], b1[j], acc[i][j], 0, 0, 0);

    // epilogue: C/D layout col = lane&15, row = quad*4 + reg; bf16 partials
    __hip_bfloat16* Pz = P + (size_t)z * BATCH * OUT;
    const int m0 = bx * 128, n0 = by * 128;
#pragma unroll
    for (int i = 0; i < 4; ++i) {
        const int r0 = m0 + mw * 64 + i * 16 + quad * 4;
#pragma unroll
        for (int j = 0; j < 4; ++j) {
            const int c = n0 + nw * 64 + j * 16 + l15;
#pragma unroll
            for (int r = 0; r < 4; ++r)
                Pz[(size_t)(r0 + r) * OUT + c] = __float2bfloat16(acc[i][j][r]);
        }
    }
}

// ---------------------------------------------------------------------------
// Kernel 3: out[b,o] = sum_z P[z][b,o] + bias[o]   (8 outputs per thread)
// ---------------------------------------------------------------------------
__global__ __launch_bounds__(256) void reducek(const short* __restrict__ P,
                                               const float* __restrict__ bias,
                                               float* __restrict__ out) {
    const int j = blockIdx.x * 256 + threadIdx.x;
    const size_t base = (size_t)j * 8;
    constexpr size_t PLANE = (size_t)BATCH * OUT;

    float s[8];
    {
        short8 v = *(const short8*)(P + base);
#pragma unroll
        for (int e = 0; e < 8; ++e) s[e] = bf16bits_to_f32(v[e]);
    }
#pragma unroll
    for (int z = 1; z < SPLITK; ++z) {
        short8 v = *(const short8*)(P + z * PLANE + base);
#pragma unroll
        for (int e = 0; e < 8; ++e) s[e] += bf16bits_to_f32(v[e]);
    }
    const int o0 = (int)(base & (OUT - 1));
    const floatx4 b0 = *(const floatx4*)(bias + o0);
    const floatx4 b1 = *(const floatx4*)(bias + o0 + 4);
    floatx4 r0 = {s[0] + b0[0], s[1] + b0[1], s[2] + b0[2], s[3] + b0[3]};
    floatx4 r1 = {s[4] + b1[0], s[5] + b1[1], s[6] + b1[2], s[7] + b1[3]};
    *(floatx4*)(out + base)     = r0;
    *(floatx4*)(out + base + 4) = r1;
}

// ---------------------------------------------------------------------------
extern "C" void kernel_launch(void* const* d_in, const int* in_sizes, int n_in,
                              void* d_out, int out_size, void* d_ws, size_t ws_size,
                              hipStream_t stream) {
    const float* x     = (const float*)d_in[0];   // [4096,512]
    const float* w     = (const float*)d_in[1];   // [512,512]
    const float* coeff = (const float*)d_in[2];   // [512,512,9]
    float* out = (float*)d_out;                   // [4096,512]

    // workspace layout (bytes)
    char* ws = (char*)d_ws;
    short* A2 = (short*)ws;                                            // 33,554,432 B
    char* p1c = ws + (size_t)BATCH * KP * 2;
    short* B2 = (short*)p1c;                                           //  4,194,304 B
    char* p2c = p1c + (size_t)OUT * KP * 2;
    __hip_bfloat16* P = (__hip_bfloat16*)p2c;                          // 16,777,216 B
    float* bias = (float*)(p2c + (size_t)SPLITK * BATCH * OUT * 2);    //      2,048 B

    prep<<<1280, 256, 0, stream>>>(x, w, coeff, A2, B2, bias);
    gemm_splitk<<<dim3(32, 4, SPLITK), 256, 0, stream>>>(A2, B2, P);
    reducek<<<BATCH * OUT / 8 / 256, 256, 0, stream>>>((const short*)P, bias, out);
}

// Round 15
// 102.843 us; speedup vs baseline: 1.1640x; 1.0054x over previous
//
#include <hip/hip_runtime.h>
#include <hip/hip_bf16.h>

// Problem constants
constexpr int BATCH = 4096;
constexpr int IN    = 512;
constexpr int OUT   = 512;
constexpr int ORD   = 8;
constexpr int NK    = ORD + 1;        // 9
constexpr float FA  = 1.0f, FB = 1.0f;

// GEMM inner dim EXCLUDES k=0 (J0 == 1 -> bias term), KP = 4096
constexpr int KP     = IN * ORD;
constexpr int SPLITK = 4;                      // 512 blocks -> 2 blocks/CU (optimum)
constexpr int KT     = KP / (32 * SPLITK);     // 32 K-steps (of 32) per block
constexpr int KS_TOT = KP / 32;                // 128 k-steps total

// Fragment-major layouts (written by prep, read by gemm):
//   A2[mt][ks] = 64 lanes x 16B, element (b = mt*16 + (lane&15),
//                K = ks*32 + (lane>>4)*8 + j)  -- exactly the MFMA A-operand.
//   B2[nt][ks] likewise with o rows. One wave frag load = lane*16B, coalesced.

typedef __attribute__((ext_vector_type(8))) short short8;   // 8 bf16
typedef __attribute__((ext_vector_type(4))) float floatx4;  // MFMA C/D

__device__ __forceinline__ float bf16bits_to_f32(short s) {
    union { unsigned int u; float f; } cv;
    cv.u = ((unsigned int)(unsigned short)s) << 16;
    return cv.f;
}
__device__ __forceinline__ short f32_to_bf16bits(float f) {
    __hip_bfloat16 h = __float2bfloat16(f);
    return *(short*)&h;
}

// ---------------------------------------------------------------------------
// Kernel 1 (fused prep):
//  blocks [0,1024):      Jacobi -> A2 fragment-major
//  blocks [1024,1152):   coeff*w -> B2 fragment-major
//  blocks [1152,1280):   bias[o] = sum_i coeff[o,i,0]*w[o,i] (1 wave per o)
// ---------------------------------------------------------------------------
__global__ __launch_bounds__(256) void prep(const float* __restrict__ x,
                                            const float* __restrict__ w,
                                            const float* __restrict__ coeff,
                                            short* __restrict__ A2,
                                            short* __restrict__ B2,
                                            float* __restrict__ bias) {
    const int bid  = blockIdx.x;
    const int tid  = threadIdx.x;
    const int lane = tid & 63;
    const int quad = lane >> 4;
    const int l15  = lane & 15;

    if (bid < 1024) {
        // ---- Jacobi branch: mt = bid/4, thread: b = mt*16+l15, 8 i's ----
        const int mt  = bid >> 2;
        const int sub = ((bid & 3) << 2) + (tid >> 6);   // 0..15
        const int b   = mt * 16 + l15;
        const int i0  = sub * 32 + quad * 8;
        const float* xr = x + (size_t)b * IN + i0;
        float t[8];
#pragma unroll
        for (int e = 0; e < 8; ++e) {
            float xc = fminf(fmaxf(xr[e], -9.0f), 9.0f);
            float ex = __expf(2.0f * xc);
            t[e] = (ex - 1.0f) / (ex + 1.0f);
        }
        float pp[8], pc[8];
#pragma unroll
        for (int e = 0; e < 8; ++e) {
            pp[e] = 1.0f;
            pc[e] = 0.5f * (FA + FB + 2.0f) * t[e] - 0.5f * (FA - FB);
        }
        {
            short8 v;
#pragma unroll
            for (int e = 0; e < 8; ++e) v[e] = f32_to_bf16bits(pc[e]);
            *(short8*)(A2 + (((size_t)mt * KS_TOT + sub) * 64 + lane) * 8) = v;
        }
#pragma unroll
        for (int n = 2; n <= ORD; ++n) {
            float fn = (float)n;
            float k1 = (2.f*fn+FA+FB)*(2.f*fn+FA+FB-1.f) / (2.f*fn*(fn+FA+FB));
            float k2 = (2.f*fn+FA+FB-1.f)*(FA*FA-FB*FB) /
                       (2.f*fn*(fn+FA+FB)*(2.f*fn+FA+FB-2.f));
            float k3 = (fn+FA-1.f)*(fn+FB-1.f)*(2.f*fn+FA+FB) /
                       (fn*(fn+FA+FB)*(2.f*fn+FA+FB-2.f));
            short8 v;
#pragma unroll
            for (int e = 0; e < 8; ++e) {
                float nx = (k1*t[e] + k2)*pc[e] - k3*pp[e];
                pp[e] = pc[e]; pc[e] = nx;
                v[e] = f32_to_bf16bits(nx);
            }
            const int ks = (n - 1) * 16 + sub;
            *(short8*)(A2 + (((size_t)mt * KS_TOT + ks) * 64 + lane) * 8) = v;
        }
    } else if (bid < 1152) {
        // ---- coeff*w branch: nt = (bid-1024)/4, o = nt*16+l15, 8 i's ----
        const int b2  = bid - 1024;
        const int nt  = b2 >> 2;
        const int sub = ((b2 & 3) << 2) + (tid >> 6);
        const int o   = nt * 16 + l15;
        const int i0  = sub * 32 + quad * 8;
        const float* wr = w + (size_t)o * IN + i0;
        float wv[8];
#pragma unroll
        for (int e = 0; e < 8; ++e) wv[e] = wr[e];
        const float* cf = coeff + ((size_t)o * IN + i0) * NK;  // [e][k] stride 9
#pragma unroll
        for (int n = 1; n <= ORD; ++n) {
            short8 v;
#pragma unroll
            for (int e = 0; e < 8; ++e)
                v[e] = f32_to_bf16bits(cf[(size_t)e * NK + n] * wv[e]);
            const int ks = (n - 1) * 16 + sub;
            *(short8*)(B2 + (((size_t)nt * KS_TOT + ks) * 64 + lane) * 8) = v;
        }
    } else {
        // ---- bias branch: 128 blocks, one wave per output o ----
        const int bb = bid - 1152;                       // 0..127
        const int o  = bb * 4 + (tid >> 6);
        const float* cf = coeff + (size_t)o * IN * NK;
        const float* wr = w + (size_t)o * IN;
        float acc = 0.0f;
#pragma unroll
        for (int r = 0; r < IN / 64; ++r) {
            int i = r * 64 + lane;
            acc = fmaf(cf[(size_t)i * NK], wr[i], acc);
        }
#pragma unroll
        for (int off = 32; off >= 1; off >>= 1)
            acc += __shfl_xor(acc, off, 64);
        if (lane == 0) bias[o] = acc;
    }
}

// ---------------------------------------------------------------------------
// Kernel 2: split-K GEMM, no LDS/barriers, 3-SLOT ROTATING PIPELINE.
// r11's 2-slot interleave (mfma s0/refill s0/mfma s1/refill s1) has
// ALTERNATING prefetch distance 2/1: slot1 is consumed one step after its
// refill issues -> every other step eats the ~900cyc cold-HBM A2 latency
// (measured: 975 cyc/wave-step). 3-slot rotation gives uniform distance-3:
// each load has 3 full MFMA phases in flight before use. Branch-free peel
// (r12's 4-slot failed on conditional refills + 128 slot regs; this is 96).
// ---------------------------------------------------------------------------
__global__ __launch_bounds__(256, 2) void gemm_splitk(
        const short* __restrict__ A2,   // [256][128] x 1KB lines
        const short* __restrict__ B2,   // [32][128]  x 1KB lines
        __hip_bfloat16* __restrict__ P) // [SPLITK][4096][512] bf16
{
    const int tid  = threadIdx.x;
    const int lane = tid & 63;
    const int quad = lane >> 4;
    const int l15  = lane & 15;
    const int mw   = (tid >> 6) & 1;
    const int nw   = tid >> 7;
    const int bx = blockIdx.x;          // 0..31  (m-tiles of 128)
    const int by = blockIdx.y;          // 0..3   (n-tiles of 128)
    const int z  = blockIdx.z;          // 0..3

    const short* pa[4];
    const short* pb[4];
#pragma unroll
    for (int i = 0; i < 4; ++i)
        pa[i] = A2 + (((size_t)(bx * 8 + mw * 4 + i) * KS_TOT + z * KT) * 64 + lane) * 8;
#pragma unroll
    for (int j = 0; j < 4; ++j)
        pb[j] = B2 + (((size_t)(by * 8 + nw * 4 + j) * KS_TOT + z * KT) * 64 + lane) * 8;

    floatx4 acc[4][4];
#pragma unroll
    for (int i = 0; i < 4; ++i)
#pragma unroll
        for (int j = 0; j < 4; ++j) acc[i][j] = (floatx4)0.0f;

#define MFMA_STEP(AS, BS)                                                   \
    _Pragma("unroll")                                                       \
    for (int i = 0; i < 4; ++i)                                             \
        _Pragma("unroll")                                                   \
        for (int j = 0; j < 4; ++j)                                         \
            acc[i][j] = __builtin_amdgcn_mfma_f32_16x16x32_bf16(            \
                            AS[i], BS[j], acc[i][j], 0, 0, 0);

#define REFILL(AS, BS, K)                                                   \
    _Pragma("unroll")                                                       \
    for (int i = 0; i < 4; ++i) {                                           \
        AS[i] = *(const short8*)(pa[i] + (K) * 512);                        \
        BS[i] = *(const short8*)(pb[i] + (K) * 512);                        \
    }

    // 3-slot pipeline: preload k = 0,1,2
    short8 a0[4], b0[4], a1[4], b1[4], a2[4], b2[4];
    REFILL(a0, b0, 0)
    REFILL(a1, b1, 1)
    REFILL(a2, b2, 2)

    // main loop: kt = 0,3,...,24  (9 iters; consumes 0..26, refills 3..29)
    for (int kt = 0; kt <= KT - 8; kt += 3) {
        MFMA_STEP(a0, b0)  REFILL(a0, b0, kt + 3)
        MFMA_STEP(a1, b1)  REFILL(a1, b1, kt + 4)
        MFMA_STEP(a2, b2)  REFILL(a2, b2, kt + 5)
    }
    // tail: slots hold k = 27,28,29
    MFMA_STEP(a0, b0)  REFILL(a0, b0, 30)   // consume 27, refill 30
    MFMA_STEP(a1, b1)  REFILL(a1, b1, 31)   // consume 28, refill 31
    MFMA_STEP(a2, b2)                        // consume 29
    MFMA_STEP(a0, b0)                        // consume 30
    MFMA_STEP(a1, b1)                        // consume 31

#undef MFMA_STEP
#undef REFILL

    // epilogue: C/D layout col = lane&15, row = quad*4 + reg; bf16 partials
    __hip_bfloat16* Pz = P + (size_t)z * BATCH * OUT;
    const int m0 = bx * 128, n0 = by * 128;
#pragma unroll
    for (int i = 0; i < 4; ++i) {
        const int r0 = m0 + mw * 64 + i * 16 + quad * 4;
#pragma unroll
        for (int j = 0; j < 4; ++j) {
            const int c = n0 + nw * 64 + j * 16 + l15;
#pragma unroll
            for (int r = 0; r < 4; ++r)
                Pz[(size_t)(r0 + r) * OUT + c] = __float2bfloat16(acc[i][j][r]);
        }
    }
}

// ---------------------------------------------------------------------------
// Kernel 3: out[b,o] = sum_z P[z][b,o] + bias[o]   (8 outputs per thread)
// ---------------------------------------------------------------------------
__global__ __launch_bounds__(256) void reducek(const short* __restrict__ P,
                                               const float* __restrict__ bias,
                                               float* __restrict__ out) {
    const int j = blockIdx.x * 256 + threadIdx.x;
    const size_t base = (size_t)j * 8;
    constexpr size_t PLANE = (size_t)BATCH * OUT;

    float s[8];
    {
        short8 v = *(const short8*)(P + base);
#pragma unroll
        for (int e = 0; e < 8; ++e) s[e] = bf16bits_to_f32(v[e]);
    }
#pragma unroll
    for (int z = 1; z < SPLITK; ++z) {
        short8 v = *(const short8*)(P + z * PLANE + base);
#pragma unroll
        for (int e = 0; e < 8; ++e) s[e] += bf16bits_to_f32(v[e]);
    }
    const int o0 = (int)(base & (OUT - 1));
    const floatx4 b0 = *(const floatx4*)(bias + o0);
    const floatx4 b1 = *(const floatx4*)(bias + o0 + 4);
    floatx4 r0 = {s[0] + b0[0], s[1] + b0[1], s[2] + b0[2], s[3] + b0[3]};
    floatx4 r1 = {s[4] + b1[0], s[5] + b1[1], s[6] + b1[2], s[7] + b1[3]};
    *(floatx4*)(out + base)     = r0;
    *(floatx4*)(out + base + 4) = r1;
}

// ---------------------------------------------------------------------------
extern "C" void kernel_launch(void* const* d_in, const int* in_sizes, int n_in,
                              void* d_out, int out_size, void* d_ws, size_t ws_size,
                              hipStream_t stream) {
    const float* x     = (const float*)d_in[0];   // [4096,512]
    const float* w     = (const float*)d_in[1];   // [512,512]
    const float* coeff = (const float*)d_in[2];   // [512,512,9]
    float* out = (float*)d_out;                   // [4096,512]

    // workspace layout (bytes)
    char* ws = (char*)d_ws;
    short* A2 = (short*)ws;                                            // 33,554,432 B
    char* p1c = ws + (size_t)BATCH * KP * 2;
    short* B2 = (short*)p1c;                                           //  4,194,304 B
    char* p2c = p1c + (size_t)OUT * KP * 2;
    __hip_bfloat16* P = (__hip_bfloat16*)p2c;                          // 16,777,216 B
    float* bias = (float*)(p2c + (size_t)SPLITK * BATCH * OUT * 2);    //      2,048 B

    prep<<<1280, 256, 0, stream>>>(x, w, coeff, A2, B2, bias);
    gemm_splitk<<<dim3(32, 4, SPLITK), 256, 0, stream>>>(A2, B2, P);
    reducek<<<BATCH * OUT / 8 / 256, 256, 0, stream>>>((const short*)P, bias, out);
}

// Round 16
// 102.062 us; speedup vs baseline: 1.1729x; 1.0077x over previous
//
#include <hip/hip_runtime.h>
#include <hip/hip_bf16.h>

// Problem constants
constexpr int BATCH = 4096;
constexpr int IN    = 512;
constexpr int OUT   = 512;
constexpr int ORD   = 8;
constexpr int NK    = ORD + 1;        // 9
constexpr float FA  = 1.0f, FB = 1.0f;

// GEMM inner dim EXCLUDES k=0 (J0 == 1 -> bias term), KP = 4096
constexpr int KP     = IN * ORD;
constexpr int SPLITK = 4;                      // 512 blocks -> 2 blocks/CU
constexpr int KT     = KP / (32 * SPLITK);     // 32 K-steps per block
constexpr int KS_TOT = KP / 32;                // 128 k-steps total

typedef __attribute__((ext_vector_type(8))) short short8;   // 8 bf16
typedef __attribute__((ext_vector_type(4))) float floatx4;  // MFMA C/D

#define AS1 __attribute__((address_space(1)))
#define AS3 __attribute__((address_space(3)))

__device__ __forceinline__ float bf16bits_to_f32(short s) {
    union { unsigned int u; float f; } cv;
    cv.u = ((unsigned int)(unsigned short)s) << 16;
    return cv.f;
}
__device__ __forceinline__ short f32_to_bf16bits(float f) {
    __hip_bfloat16 h = __float2bfloat16(f);
    return *(short*)&h;
}

// ---------------------------------------------------------------------------
// Kernel 1 (fused prep): unchanged from r11/r15.
// ---------------------------------------------------------------------------
__global__ __launch_bounds__(256) void prep(const float* __restrict__ x,
                                            const float* __restrict__ w,
                                            const float* __restrict__ coeff,
                                            short* __restrict__ A2,
                                            short* __restrict__ B2,
                                            float* __restrict__ bias) {
    const int bid  = blockIdx.x;
    const int tid  = threadIdx.x;
    const int lane = tid & 63;
    const int quad = lane >> 4;
    const int l15  = lane & 15;

    if (bid < 1024) {
        const int mt  = bid >> 2;
        const int sub = ((bid & 3) << 2) + (tid >> 6);   // 0..15
        const int b   = mt * 16 + l15;
        const int i0  = sub * 32 + quad * 8;
        const float* xr = x + (size_t)b * IN + i0;
        float t[8];
#pragma unroll
        for (int e = 0; e < 8; ++e) {
            float xc = fminf(fmaxf(xr[e], -9.0f), 9.0f);
            float ex = __expf(2.0f * xc);
            t[e] = (ex - 1.0f) / (ex + 1.0f);
        }
        float pp[8], pc[8];
#pragma unroll
        for (int e = 0; e < 8; ++e) {
            pp[e] = 1.0f;
            pc[e] = 0.5f * (FA + FB + 2.0f) * t[e] - 0.5f * (FA - FB);
        }
        {
            short8 v;
#pragma unroll
            for (int e = 0; e < 8; ++e) v[e] = f32_to_bf16bits(pc[e]);
            *(short8*)(A2 + (((size_t)mt * KS_TOT + sub) * 64 + lane) * 8) = v;
        }
#pragma unroll
        for (int n = 2; n <= ORD; ++n) {
            float fn = (float)n;
            float k1 = (2.f*fn+FA+FB)*(2.f*fn+FA+FB-1.f) / (2.f*fn*(fn+FA+FB));
            float k2 = (2.f*fn+FA+FB-1.f)*(FA*FA-FB*FB) /
                       (2.f*fn*(fn+FA+FB)*(2.f*fn+FA+FB-2.f));
            float k3 = (fn+FA-1.f)*(fn+FB-1.f)*(2.f*fn+FA+FB) /
                       (fn*(fn+FA+FB)*(2.f*fn+FA+FB-2.f));
            short8 v;
#pragma unroll
            for (int e = 0; e < 8; ++e) {
                float nx = (k1*t[e] + k2)*pc[e] - k3*pp[e];
                pp[e] = pc[e]; pc[e] = nx;
                v[e] = f32_to_bf16bits(nx);
            }
            const int ks = (n - 1) * 16 + sub;
            *(short8*)(A2 + (((size_t)mt * KS_TOT + ks) * 64 + lane) * 8) = v;
        }
    } else if (bid < 1152) {
        const int b2  = bid - 1024;
        const int nt  = b2 >> 2;
        const int sub = ((b2 & 3) << 2) + (tid >> 6);
        const int o   = nt * 16 + l15;
        const int i0  = sub * 32 + quad * 8;
        const float* wr = w + (size_t)o * IN + i0;
        float wv[8];
#pragma unroll
        for (int e = 0; e < 8; ++e) wv[e] = wr[e];
        const float* cf = coeff + ((size_t)o * IN + i0) * NK;
#pragma unroll
        for (int n = 1; n <= ORD; ++n) {
            short8 v;
#pragma unroll
            for (int e = 0; e < 8; ++e)
                v[e] = f32_to_bf16bits(cf[(size_t)e * NK + n] * wv[e]);
            const int ks = (n - 1) * 16 + sub;
            *(short8*)(B2 + (((size_t)nt * KS_TOT + ks) * 64 + lane) * 8) = v;
        }
    } else {
        const int bb = bid - 1152;
        const int o  = bb * 4 + (tid >> 6);
        const float* cf = coeff + (size_t)o * IN * NK;
        const float* wr = w + (size_t)o * IN;
        float acc = 0.0f;
#pragma unroll
        for (int r = 0; r < IN / 64; ++r) {
            int i = r * 64 + lane;
            acc = fmaf(cf[(size_t)i * NK], wr[i], acc);
        }
#pragma unroll
        for (int off = 32; off >= 1; off >>= 1)
            acc += __shfl_xor(acc, off, 64);
        if (lane == 0) bias[o] = acc;
    }
}

// ---------------------------------------------------------------------------
// Kernel 2: HYBRID split-K GEMM.
// Theory (r15 post-mortem): no-LDS design saturates L1 (64 KB/CU-step @
// ~64 B/cyc = measured ~1000 cyc/step); LDS-only design saturates LDS pipe.
// Split: A staged via double-buffered LDS (4-step batches, ONE barrier per
// batch, stage loads get ~4 steps in flight before the drain), B direct via
// L1 with the r11 2-slot register pipeline.
//   Per CU-step: L1 = B 32 KB (~500cyc), LDS = A 48 KB (~375cyc) -> ~585 cyc
//   (L2-share floor) vs measured 1000.
// ---------------------------------------------------------------------------
__global__ __launch_bounds__(256, 2) void gemm_splitk(
        const short* __restrict__ A2,   // [256][128] x 1KB lines
        const short* __restrict__ B2,   // [32][128]  x 1KB lines
        __hip_bfloat16* __restrict__ P) // [SPLITK][4096][512] bf16
{
    // 2 buffers x 4 steps x 8 m-lines x 512 shorts = 64 KB
    __shared__ short sA[2 * 4 * 8 * 512];

    const int tid  = threadIdx.x;
    const int lane = tid & 63;
    const int quad = lane >> 4;
    const int l15  = lane & 15;
    const int mw   = (tid >> 6) & 1;
    const int nw   = tid >> 7;
    const int bx = blockIdx.x;          // 0..31  (m-tiles of 128)
    const int by = blockIdx.y;          // 0..3   (n-tiles of 128)
    const int z  = blockIdx.z;          // 0..3

    // B direct pointers (register pipeline)
    const short* pb[4];
#pragma unroll
    for (int j = 0; j < 4; ++j)
        pb[j] = B2 + (((size_t)(by * 8 + nw * 4 + j) * KS_TOT + z * KT) * 64 + lane) * 8;

    // A staging: call c stages line ll = c*4 + (tid>>6); mt = ll&7, s = ll>>3.
    // LDS layout within a buffer: [s][mt] lines of 512 shorts, lane-contiguous.
    const int wv = tid >> 6;
    const short* aBase = A2 + ((size_t)(bx * 8) * KS_TOT + z * KT) * 512;

#define STAGE(BT, BUF)                                                       \
    _Pragma("unroll")                                                        \
    for (int c = 0; c < 8; ++c) {                                            \
        const int ll = c * 4 + wv;                                           \
        const int mt = ll & 7;                                               \
        const int s  = ll >> 3;                                              \
        __builtin_amdgcn_global_load_lds(                                    \
            (const AS1 unsigned int*)(aBase +                                \
                ((size_t)mt * KS_TOT + (BT) * 4 + s) * 512 + lane * 8),      \
            (AS3 unsigned int*)(sA + (BUF) * 16384 + (c * 256 + tid) * 8),   \
            16, 0, 0);                                                       \
    }

    floatx4 acc[4][4];
#pragma unroll
    for (int i = 0; i < 4; ++i)
#pragma unroll
        for (int j = 0; j < 4; ++j) acc[i][j] = (floatx4)0.0f;

    // B 2-slot preload (k = 0, 1)
    short8 bs0[4], bs1[4];
#pragma unroll
    for (int j = 0; j < 4; ++j) { bs0[j] = *(const short8*)(pb[j]);
                                  bs1[j] = *(const short8*)(pb[j] + 512); }

    // A: stage batch 0
    STAGE(0, 0)
    __syncthreads();                    // batch 0 resident

#define ASTEP(BUF, S, BSLOT, KREF, DOREF)                                    \
    {                                                                        \
        short8 af[4];                                                        \
        _Pragma("unroll")                                                    \
        for (int i = 0; i < 4; ++i)                                          \
            af[i] = *(const short8*)(sA + (BUF) * 16384 +                    \
                        (((S) * 8 + mw * 4 + i) * 64 + lane) * 8);           \
        _Pragma("unroll")                                                    \
        for (int i = 0; i < 4; ++i)                                          \
            _Pragma("unroll")                                                \
            for (int j = 0; j < 4; ++j)                                      \
                acc[i][j] = __builtin_amdgcn_mfma_f32_16x16x32_bf16(         \
                                af[i], BSLOT[j], acc[i][j], 0, 0, 0);        \
        if (DOREF) {                                                         \
            _Pragma("unroll")                                                \
            for (int j = 0; j < 4; ++j)                                      \
                BSLOT[j] = *(const short8*)(pb[j] + (KREF) * 512);           \
        }                                                                    \
    }

    // batches 0..6: stage next batch, 4 steps, barrier
    for (int bt = 0; bt < 7; ++bt) {
        const int buf = bt & 1;
        STAGE(bt + 1, buf ^ 1)
        const int k0 = bt * 4;          // even
        ASTEP(buf, 0, bs0, k0 + 2, true)
        ASTEP(buf, 1, bs1, k0 + 3, true)
        ASTEP(buf, 2, bs0, k0 + 4, true)
        ASTEP(buf, 3, bs1, k0 + 5, true)
        __syncthreads();                // next batch resident; this buf free
    }
    // batch 7 (buf 1): k = 28,29 refill 30,31; k = 30,31 no refill
    ASTEP(1, 0, bs0, 30, true)
    ASTEP(1, 1, bs1, 31, true)
    ASTEP(1, 2, bs0, 0, false)
    ASTEP(1, 3, bs1, 0, false)

#undef ASTEP
#undef STAGE

    // epilogue: C/D layout col = lane&15, row = quad*4 + reg; bf16 partials
    __hip_bfloat16* Pz = P + (size_t)z * BATCH * OUT;
    const int m0 = bx * 128, n0 = by * 128;
#pragma unroll
    for (int i = 0; i < 4; ++i) {
        const int r0 = m0 + mw * 64 + i * 16 + quad * 4;
#pragma unroll
        for (int j = 0; j < 4; ++j) {
            const int c = n0 + nw * 64 + j * 16 + l15;
#pragma unroll
            for (int r = 0; r < 4; ++r)
                Pz[(size_t)(r0 + r) * OUT + c] = __float2bfloat16(acc[i][j][r]);
        }
    }
}

// ---------------------------------------------------------------------------
// Kernel 3: out[b,o] = sum_z P[z][b,o] + bias[o]   (8 outputs per thread)
// ---------------------------------------------------------------------------
__global__ __launch_bounds__(256) void reducek(const short* __restrict__ P,
                                               const float* __restrict__ bias,
                                               float* __restrict__ out) {
    const int j = blockIdx.x * 256 + threadIdx.x;
    const size_t base = (size_t)j * 8;
    constexpr size_t PLANE = (size_t)BATCH * OUT;

    float s[8];
    {
        short8 v = *(const short8*)(P + base);
#pragma unroll
        for (int e = 0; e < 8; ++e) s[e] = bf16bits_to_f32(v[e]);
    }
#pragma unroll
    for (int z = 1; z < SPLITK; ++z) {
        short8 v = *(const short8*)(P + z * PLANE + base);
#pragma unroll
        for (int e = 0; e < 8; ++e) s[e] += bf16bits_to_f32(v[e]);
    }
    const int o0 = (int)(base & (OUT - 1));
    const floatx4 b0 = *(const floatx4*)(bias + o0);
    const floatx4 b1 = *(const floatx4*)(bias + o0 + 4);
    floatx4 r0 = {s[0] + b0[0], s[1] + b0[1], s[2] + b0[2], s[3] + b0[3]};
    floatx4 r1 = {s[4] + b1[0], s[5] + b1[1], s[6] + b1[2], s[7] + b1[3]};
    *(floatx4*)(out + base)     = r0;
    *(floatx4*)(out + base + 4) = r1;
}

// ---------------------------------------------------------------------------
extern "C" void kernel_launch(void* const* d_in, const int* in_sizes, int n_in,
                              void* d_out, int out_size, void* d_ws, size_t ws_size,
                              hipStream_t stream) {
    const float* x     = (const float*)d_in[0];   // [4096,512]
    const float* w     = (const float*)d_in[1];   // [512,512]
    const float* coeff = (const float*)d_in[2];   // [512,512,9]
    float* out = (float*)d_out;                   // [4096,512]

    // workspace layout (bytes)
    char* ws = (char*)d_ws;
    short* A2 = (short*)ws;                                            // 33,554,432 B
    char* p1c = ws + (size_t)BATCH * KP * 2;
    short* B2 = (short*)p1c;                                           //  4,194,304 B
    char* p2c = p1c + (size_t)OUT * KP * 2;
    __hip_bfloat16* P = (__hip_bfloat16*)p2c;                          // 16,777,216 B
    float* bias = (float*)(p2c + (size_t)SPLITK * BATCH * OUT * 2);    //      2,048 B

    prep<<<1280, 256, 0, stream>>>(x, w, coeff, A2, B2, bias);
    gemm_splitk<<<dim3(32, 4, SPLITK), 256, 0, stream>>>(A2, B2, P);
    reducek<<<BATCH * OUT / 8 / 256, 256, 0, stream>>>((const short*)P, bias, out);
}